// Round 8
// baseline (478.086 us; speedup 1.0000x reference)
//
#include <hip/hip_runtime.h>

#define PRE   1024
#define POST  1024
#define BATCH 256
#define HIST  50
#define NPAIR (PRE * POST)

typedef float nf4 __attribute__((ext_vector_type(4)));   // native vecs for nontemporal builtins
typedef float nf2 __attribute__((ext_vector_type(2)));

// ================= fused kernel A: means (blocks 0..127) + gemm (128..639) =================
#define MCOLS 16
#define GBM 64
#define GBN 64
#define GBK 16
#define GKSPLIT 8
#define GLD 68                      // padded leading dim for As/Bs

__global__ __launch_bounds__(256) void fusedA_kernel(
    const float* __restrict__ pre_spikes,   // [BATCH, PRE]  (= gemm A)
    const float* __restrict__ post_spikes,  // [BATCH, POST]
    const float* __restrict__ pre_activity, // [PRE]
    const float* __restrict__ post_activity,// [POST]
    float* __restrict__ ws_means,           // [PRE + POST] scratch
    float* __restrict__ out_pre_act,        // [PRE]
    float* __restrict__ out_post_act,       // [POST]
    const float* __restrict__ W,            // [PRE, POST]
    const float* __restrict__ Mk,           // [PRE, POST]
    float* __restrict__ C,                  // [BATCH, POST] (atomic path)
    float* __restrict__ Cpart,              // [GKSPLIT, BATCH*POST] (partial path)
    int use_part)
{
    int tid = threadIdx.x;

    if (blockIdx.x < 128) {
        // ---------------- means + EMA (R5-proven core) ----------------
        __shared__ float red[256];
        int blk = blockIdx.x;                  // 0..127
        bool is_pre = blk < 64;
        const float* mat = is_pre ? pre_spikes : post_spikes;
        const float* act = is_pre ? pre_activity : post_activity;
        float* out_act   = is_pre ? out_pre_act : out_post_act;
        float* ws        = is_pre ? ws_means : ws_means + PRE;
        int col0 = (blk & 63) * MCOLS;

        int col = col0 + (tid & 15);
        int chunk = tid >> 4;                  // 0..15, 16 rows each
        float s = 0.f;
#pragma unroll
        for (int r = chunk * 16; r < chunk * 16 + 16; ++r)
            s += mat[r * 1024 + col];
        red[tid] = s;
        __syncthreads();
        if (tid < 16) {
            float t = 0.f;
#pragma unroll
            for (int k = 0; k < 16; ++k)
                t += red[k * 16 + tid];
            float m = t * (1.0f / BATCH);
            int c = col0 + tid;
            ws[c] = m;
            out_act[c] = 0.99f * act[c] + 0.01f * m;
        }
        return;
    }

    // ---------------- masked SGEMM 64x64, 4x4/thread, split-K x8 (R6-proven core) ----------------
    __shared__ __align__(16) float As[GBK * GLD];   // As[k][m] (transposed)
    __shared__ __align__(16) float Bs[GBK * GLD];   // Bs[k][n]
    int id = blockIdx.x - 128;     // 0..511
    int bn = id & 15;
    int bm = (id >> 4) & 3;
    int bz = id >> 6;
    int kbase = bz * (PRE / GKSPLIT);

    int ar = tid >> 2;
    int ak = (tid & 3) << 2;
    int bk = tid >> 4;
    int bn4 = (tid & 15) << 2;
    int tn4 = (tid & 15) << 2;
    int tm4 = (tid >> 4) << 2;

    const float* Ap = &pre_spikes[(bm * GBM + ar) * PRE + kbase + ak];
    const float* Wp = &W [(size_t)(kbase + bk) * POST + bn * GBN + bn4];
    const float* Mp = &Mk[(size_t)(kbase + bk) * POST + bn * GBN + bn4];

    float acc[4][4] = {};

    for (int k0 = 0; k0 < PRE / GKSPLIT; k0 += GBK) {
        float4 av = *(const float4*)(Ap + k0);
        float4 wv = *(const float4*)(Wp + (size_t)k0 * POST);
        float4 mv = *(const float4*)(Mp + (size_t)k0 * POST);
        wv.x *= mv.x; wv.y *= mv.y; wv.z *= mv.z; wv.w *= mv.w;
        __syncthreads();                       // protect previous iter's reads
        As[(ak + 0) * GLD + ar] = av.x;
        As[(ak + 1) * GLD + ar] = av.y;
        As[(ak + 2) * GLD + ar] = av.z;
        As[(ak + 3) * GLD + ar] = av.w;
        *(float4*)&Bs[bk * GLD + bn4] = wv;
        __syncthreads();
#pragma unroll
        for (int kk = 0; kk < GBK; ++kk) {
            float4 a4 = *(const float4*)&As[kk * GLD + tm4];
            float4 b4 = *(const float4*)&Bs[kk * GLD + tn4];
            const float* ap = (const float*)&a4;
            const float* bp = (const float*)&b4;
#pragma unroll
            for (int i = 0; i < 4; ++i)
#pragma unroll
                for (int j = 0; j < 4; ++j)
                    acc[i][j] += ap[i] * bp[j];
        }
    }
    if (use_part) {
        float* dst = &Cpart[(size_t)bz * (BATCH * POST)
                            + (size_t)(bm * GBM + tm4) * POST + bn * GBN + tn4];
#pragma unroll
        for (int i = 0; i < 4; ++i) {
            float4 r; r.x = acc[i][0]; r.y = acc[i][1]; r.z = acc[i][2]; r.w = acc[i][3];
            *(float4*)(dst + (size_t)i * POST) = r;
        }
    } else {
#pragma unroll
        for (int i = 0; i < 4; ++i)
#pragma unroll
            for (int j = 0; j < 4; ++j)
                atomicAdd(&C[(size_t)(bm * GBM + tm4 + i) * POST + bn * GBN + tn4 + j],
                          acc[i][j]);
    }
}

// ================= fused kernel B: gemm-reduce (first nred blocks) + history =================
// reduce: 256 blocks x 256 thr, guard-free (65536 float4s).
// history R8: 2 threads per pair (even/odd float2 interleave). Thread (pl,h)
// owns pair-offsets 4k+2h (h=0: k<13, h=1: k<12 -> exactly 50 floats, always
// 8B-aligned). Register-only pipeline: nt float2 loads -> static-unrolled
// slot-idx substitute (k compile-time: no scratch) -> plain cacheable float2
// stores (L2 write-combines the interleave) -> in-register sum -> shfl_xor(1)
// -> avg. NO LDS, NO barrier, no serial tail: removes the per-block critical
// path that kept history ~20us above its BW roofline. Risk (stated): ~50
// line-touches per wave-instr vs 8; L1/L2 absorb re-touches (per-XCD working
// set << 4MB) so HBM traffic is unchanged.
#define HPB 128
#define NRED 256                   // 65536 / 256

__global__ __launch_bounds__(256) void fusedB_kernel(
    const float* __restrict__ hist_in,    // [PRE, POST, HIST]
    const int*   __restrict__ corr_index, // scalar
    const float* __restrict__ ws_means,   // [PRE + POST]
    float* __restrict__ hist_out,         // [PRE, POST, HIST]
    float* __restrict__ avg_out,          // [PRE, POST]
    const float* __restrict__ Cpart,      // [GKSPLIT, BATCH*POST]
    float* __restrict__ C,                // [BATCH*POST]
    int nred)
{
    int tid = threadIdx.x;

    if ((int)blockIdx.x < nred) {
        // ---------------- split-K reduce ----------------
        int g = blockIdx.x * 256 + tid;             // float4 index, < 65536
        const nf4* p4 = (const nf4*)Cpart;
        nf4 s = p4[g];
#pragma unroll
        for (int z = 1; z < GKSPLIT; ++z)
            s += p4[(size_t)z * (BATCH * POST / 4) + g];
        ((nf4*)C)[g] = s;
        return;
    }

    // ---------------- history: register-only copy + scatter + mean ----------------
    int b  = (int)blockIdx.x - nred;
    int pl = tid >> 1;
    int h  = tid & 1;
    int p  = b * HPB + pl;                          // global pair
    int idx = ((corr_index[0] % HIST) + HIST) % HIST;

    const float* ibase = hist_in  + (size_t)p * HIST + 2 * h;
    float*       obase = hist_out + (size_t)p * HIST + 2 * h;
    int nk = 13 - h;                                // h=0: 13 float2s, h=1: 12

    nf2 v[13];
#pragma unroll
    for (int k = 0; k < 13; ++k)
        if (k < nk)
            v[k] = __builtin_nontemporal_load((const nf2*)(ibase + 4 * k));

    // slot idx -> (hneed, kidx, comp):  idx = 4*kidx + 2*hneed + comp
    float corr = ws_means[p >> 10] * ws_means[PRE + (p & (POST - 1))];
    bool hm  = (h == ((idx >> 1) & 1));
    int kidx = idx >> 2;
    int comp = idx & 1;
#pragma unroll
    for (int k = 0; k < 13; ++k)
        if (k < nk) {
            bool m = hm && (k == kidx);
            v[k].x = (m && comp == 0) ? corr : v[k].x;
            v[k].y = (m && comp == 1) ? corr : v[k].y;
        }

    float s = 0.f;
#pragma unroll
    for (int k = 0; k < 13; ++k)
        if (k < nk) {
            *(nf2*)(obase + 4 * k) = v[k];          // cacheable: L2 write-combine
            s += v[k].x + v[k].y;
        }

    s += __shfl_xor(s, 1);                          // partner = other half of pair
    if (h == 0)
        avg_out[p] = s * (1.0f / HIST);
}

extern "C" void kernel_launch(void* const* d_in, const int* in_sizes, int n_in,
                              void* d_out, int out_size, void* d_ws, size_t ws_size,
                              hipStream_t stream)
{
    const float* pre_spikes  = (const float*)d_in[0];
    const float* post_spikes = (const float*)d_in[1];
    const float* W           = (const float*)d_in[2];
    const float* Mk          = (const float*)d_in[3];
    const float* hist        = (const float*)d_in[4];
    const float* pre_act     = (const float*)d_in[5];
    const float* post_act    = (const float*)d_in[6];
    const int*   corr_index  = (const int*)d_in[7];

    float* out = (float*)d_out;
    float* out_current  = out;                          // [256,1024]   262144
    float* out_pre_act  = out + 262144;                 // [1024]
    float* out_post_act = out + 263168;                 // [1024]
    float* out_avg      = out + 264192;                 // [1024,1024]  1048576
    float* out_hist     = out + 1312768;                // [1024,1024,50]

    float* ws_means = (float*)d_ws;                     // 2048 floats (+pad)
    float* cpart    = ws_means + 4096;                  // 16 KB offset, aligned
    size_t ws_need  = (size_t)4096 * 4 + (size_t)GKSPLIT * BATCH * POST * 4; // 16KB + 8MB
    int use_part    = ws_size >= ws_need;

    if (!use_part)
        (void)hipMemsetAsync(out_current, 0, (size_t)BATCH * POST * sizeof(float), stream);

    fusedA_kernel<<<128 + 512, 256, 0, stream>>>(
        pre_spikes, post_spikes, pre_act, post_act,
        ws_means, out_pre_act, out_post_act,
        W, Mk, out_current, cpart, use_part);

    int nred = use_part ? NRED : 0;
    fusedB_kernel<<<nred + NPAIR / HPB, 256, 0, stream>>>(
        hist, corr_index, ws_means, out_hist, out_avg,
        cpart, out_current, nred);
}

// Round 9
// 371.646 us; speedup vs baseline: 1.2864x; 1.2864x over previous
//
#include <hip/hip_runtime.h>

#define PRE   1024
#define POST  1024
#define BATCH 256
#define HIST  50
#define NPAIR (PRE * POST)

typedef float nf4 __attribute__((ext_vector_type(4)));   // native vecs for nontemporal builtins
typedef float nf2 __attribute__((ext_vector_type(2)));

// ================= fused kernel A: means (blocks 0..127) + gemm (128..639) =================
#define MCOLS 16
#define GBM 64
#define GBN 64
#define GBK 16
#define GKSPLIT 8
#define GLD 68                      // padded leading dim for As/Bs

__global__ __launch_bounds__(256) void fusedA_kernel(
    const float* __restrict__ pre_spikes,   // [BATCH, PRE]  (= gemm A)
    const float* __restrict__ post_spikes,  // [BATCH, POST]
    const float* __restrict__ pre_activity, // [PRE]
    const float* __restrict__ post_activity,// [POST]
    float* __restrict__ ws_means,           // [PRE + POST] scratch
    float* __restrict__ out_pre_act,        // [PRE]
    float* __restrict__ out_post_act,       // [POST]
    const float* __restrict__ W,            // [PRE, POST]
    const float* __restrict__ Mk,           // [PRE, POST]
    float* __restrict__ C,                  // [BATCH, POST] (atomic path)
    float* __restrict__ Cpart,              // [GKSPLIT, BATCH*POST] (partial path)
    int use_part)
{
    int tid = threadIdx.x;

    if (blockIdx.x < 128) {
        // ---------------- means + EMA (R5-proven core) ----------------
        __shared__ float red[256];
        int blk = blockIdx.x;                  // 0..127
        bool is_pre = blk < 64;
        const float* mat = is_pre ? pre_spikes : post_spikes;
        const float* act = is_pre ? pre_activity : post_activity;
        float* out_act   = is_pre ? out_pre_act : out_post_act;
        float* ws        = is_pre ? ws_means : ws_means + PRE;
        int col0 = (blk & 63) * MCOLS;

        int col = col0 + (tid & 15);
        int chunk = tid >> 4;                  // 0..15, 16 rows each
        float s = 0.f;
#pragma unroll
        for (int r = chunk * 16; r < chunk * 16 + 16; ++r)
            s += mat[r * 1024 + col];
        red[tid] = s;
        __syncthreads();
        if (tid < 16) {
            float t = 0.f;
#pragma unroll
            for (int k = 0; k < 16; ++k)
                t += red[k * 16 + tid];
            float m = t * (1.0f / BATCH);
            int c = col0 + tid;
            ws[c] = m;
            out_act[c] = 0.99f * act[c] + 0.01f * m;
        }
        return;
    }

    // ---------------- masked SGEMM 64x64, 4x4/thread, split-K x8 (R6-proven core) ----------------
    __shared__ __align__(16) float As[GBK * GLD];   // As[k][m] (transposed)
    __shared__ __align__(16) float Bs[GBK * GLD];   // Bs[k][n]
    int id = blockIdx.x - 128;     // 0..511
    int bn = id & 15;
    int bm = (id >> 4) & 3;
    int bz = id >> 6;
    int kbase = bz * (PRE / GKSPLIT);

    int ar = tid >> 2;
    int ak = (tid & 3) << 2;
    int bk = tid >> 4;
    int bn4 = (tid & 15) << 2;
    int tn4 = (tid & 15) << 2;
    int tm4 = (tid >> 4) << 2;

    const float* Ap = &pre_spikes[(bm * GBM + ar) * PRE + kbase + ak];
    const float* Wp = &W [(size_t)(kbase + bk) * POST + bn * GBN + bn4];
    const float* Mp = &Mk[(size_t)(kbase + bk) * POST + bn * GBN + bn4];

    float acc[4][4] = {};

    for (int k0 = 0; k0 < PRE / GKSPLIT; k0 += GBK) {
        float4 av = *(const float4*)(Ap + k0);
        float4 wv = *(const float4*)(Wp + (size_t)k0 * POST);
        float4 mv = *(const float4*)(Mp + (size_t)k0 * POST);
        wv.x *= mv.x; wv.y *= mv.y; wv.z *= mv.z; wv.w *= mv.w;
        __syncthreads();                       // protect previous iter's reads
        As[(ak + 0) * GLD + ar] = av.x;
        As[(ak + 1) * GLD + ar] = av.y;
        As[(ak + 2) * GLD + ar] = av.z;
        As[(ak + 3) * GLD + ar] = av.w;
        *(float4*)&Bs[bk * GLD + bn4] = wv;
        __syncthreads();
#pragma unroll
        for (int kk = 0; kk < GBK; ++kk) {
            float4 a4 = *(const float4*)&As[kk * GLD + tm4];
            float4 b4 = *(const float4*)&Bs[kk * GLD + tn4];
            const float* ap = (const float*)&a4;
            const float* bp = (const float*)&b4;
#pragma unroll
            for (int i = 0; i < 4; ++i)
#pragma unroll
                for (int j = 0; j < 4; ++j)
                    acc[i][j] += ap[i] * bp[j];
        }
    }
    if (use_part) {
        float* dst = &Cpart[(size_t)bz * (BATCH * POST)
                            + (size_t)(bm * GBM + tm4) * POST + bn * GBN + tn4];
#pragma unroll
        for (int i = 0; i < 4; ++i) {
            float4 r; r.x = acc[i][0]; r.y = acc[i][1]; r.z = acc[i][2]; r.w = acc[i][3];
            *(float4*)(dst + (size_t)i * POST) = r;
        }
    } else {
#pragma unroll
        for (int i = 0; i < 4; ++i)
#pragma unroll
            for (int j = 0; j < 4; ++j)
                atomicAdd(&C[(size_t)(bm * GBM + tm4 + i) * POST + bn * GBN + tn4 + j],
                          acc[i][j]);
    }
}

// ================= fused kernel B: gemm-reduce (first nred blocks) + history =================
// reduce: 256 blocks x 256 thr, guard-free (65536 float4s).
// history R9: R7's coalesced float4 pipeline with a WAVE-PRIVATE LDS tile.
// Each 64-lane wave owns 32 whole pairs (1600 floats = 400 float4s,
// contiguous): 7 guarded nt float4 loads/lane -> substitute -> LDS write +
// nt store (fire-and-forget) -> wave-local tail (2 lanes/pair x 32 pairs =
// 64 lanes, 13 guarded float2 LDS reads, shfl_xor(1)). Writer==reader wave,
// so NO __syncthreads: ordering is the compiler's lgkmcnt wait on this
// wave's own ds_writes. Stores overlap the tail. Coalescing: every wave VMEM
// op is 1024B contiguous (8 lines) -- R8's 50-line scatter is gone.
#define HPB 128                    // pairs per block (4 waves x 32)
#define WPAIRS 32
#define WF4 400                    // float4s per wave (32*50/4)
#define NRED 256                   // 65536 / 256

__global__ __launch_bounds__(256) void fusedB_kernel(
    const float* __restrict__ hist_in,    // [PRE, POST, HIST]
    const int*   __restrict__ corr_index, // scalar
    const float* __restrict__ ws_means,   // [PRE + POST]
    float* __restrict__ hist_out,         // [PRE, POST, HIST]
    float* __restrict__ avg_out,          // [PRE, POST]
    const float* __restrict__ Cpart,      // [GKSPLIT, BATCH*POST]
    float* __restrict__ C,                // [BATCH*POST]
    int nred)
{
    int tid = threadIdx.x;

    if ((int)blockIdx.x < nred) {
        // ---------------- split-K reduce ----------------
        int g = blockIdx.x * 256 + tid;             // float4 index, < 65536
        const nf4* p4 = (const nf4*)Cpart;
        nf4 s = p4[g];
#pragma unroll
        for (int z = 1; z < GKSPLIT; ++z)
            s += p4[(size_t)z * (BATCH * POST / 4) + g];
        ((nf4*)C)[g] = s;
        return;
    }

    // ---------------- history: wave-private copy + scatter + mean ----------------
    __shared__ __align__(16) float tile[4 * WPAIRS * HIST + 2];   // 25608 B (+2 pad)
    int b    = (int)blockIdx.x - nred;
    int wid  = tid >> 6;
    int lane = tid & 63;
    int wp0  = b * HPB + wid * WPAIRS;              // first pair owned by wave
    int idx  = ((corr_index[0] % HIST) + HIST) % HIST;

    const nf4* in4  = (const nf4*)hist_in  + (size_t)b * 1600 + wid * WF4;
    nf4*       out4 = (nf4*)hist_out       + (size_t)b * 1600 + wid * WF4;
    float*     wt   = tile + wid * (WPAIRS * HIST); // wave's 1600-float region
    nf4*       wt4  = (nf4*)wt;

    nf4 v[7];
#pragma unroll
    for (int k = 0; k < 7; ++k) {
        int fl = k * 64 + lane;
        if (fl < WF4)
            v[k] = __builtin_nontemporal_load(&in4[fl]);
    }

#pragma unroll
    for (int k = 0; k < 7; ++k) {
        int fl = k * 64 + lane;
        if (fl < WF4) {
            int r0 = 4 * fl;               // float offset within wave region
            int pl = r0 / HIST;            // local pair of component 0 (0..31)
            int t0 = r0 - pl * HIST;       // slot of component 0 (even, 0..48)
            int d  = idx - t0;             // component holding slot idx (pair pl)
            int d2 = idx + HIST - t0;      // component holding slot idx (pair pl+1), >= 2
            bool needA = ((unsigned)d) < 4u;
            bool needB = (d2 < 4);         // implies t0 == 48 (pl <= 30); disjoint from needA
            float corr = 0.f;
            if (needA | needB) {           // rare: ~8% of float4s
                int pair = needA ? (wp0 + pl) : (wp0 + pl + 1);
                corr = ws_means[pair >> 10] * ws_means[PRE + (pair & (POST - 1))];
            }
            nf4 w = v[k];
            w.x = (d == 0) ? corr : w.x;
            w.y = (d == 1) ? corr : w.y;
            w.z = (d == 2 || d2 == 2) ? corr : w.z;
            w.w = (d == 3 || d2 == 3) ? corr : w.w;
            wt4[fl] = w;                                   // wave-local LDS
            __builtin_nontemporal_store(w, &out4[fl]);     // fire-and-forget
        }
    }

    // wave-local tail: 2 lanes/pair x 32 pairs; reader==writer wave, so the
    // compiler's lgkmcnt wait on our own ds_writes is the only sync needed.
    int pl   = lane >> 1;
    int half = lane & 1;
    const nf2* tp = (const nf2*)(wt + pl * HIST);
    float s = 0.f;
#pragma unroll
    for (int k = 0; k < 13; ++k) {         // float2 indices half, half+2, ...
        int f2 = 2 * k + half;
        nf2 w = tp[f2];                    // f2==25 over-read lands in pad
        if (f2 < 25) s += w.x + w.y;
    }
    s += __shfl_xor(s, 1);
    if (half == 0)
        __builtin_nontemporal_store(s * (1.0f / HIST), &avg_out[wp0 + pl]);
}

extern "C" void kernel_launch(void* const* d_in, const int* in_sizes, int n_in,
                              void* d_out, int out_size, void* d_ws, size_t ws_size,
                              hipStream_t stream)
{
    const float* pre_spikes  = (const float*)d_in[0];
    const float* post_spikes = (const float*)d_in[1];
    const float* W           = (const float*)d_in[2];
    const float* Mk          = (const float*)d_in[3];
    const float* hist        = (const float*)d_in[4];
    const float* pre_act     = (const float*)d_in[5];
    const float* post_act    = (const float*)d_in[6];
    const int*   corr_index  = (const int*)d_in[7];

    float* out = (float*)d_out;
    float* out_current  = out;                          // [256,1024]   262144
    float* out_pre_act  = out + 262144;                 // [1024]
    float* out_post_act = out + 263168;                 // [1024]
    float* out_avg      = out + 264192;                 // [1024,1024]  1048576
    float* out_hist     = out + 1312768;                // [1024,1024,50]

    float* ws_means = (float*)d_ws;                     // 2048 floats (+pad)
    float* cpart    = ws_means + 4096;                  // 16 KB offset, aligned
    size_t ws_need  = (size_t)4096 * 4 + (size_t)GKSPLIT * BATCH * POST * 4; // 16KB + 8MB
    int use_part    = ws_size >= ws_need;

    if (!use_part)
        (void)hipMemsetAsync(out_current, 0, (size_t)BATCH * POST * sizeof(float), stream);

    fusedA_kernel<<<128 + 512, 256, 0, stream>>>(
        pre_spikes, post_spikes, pre_act, post_act,
        ws_means, out_pre_act, out_post_act,
        W, Mk, out_current, cpart, use_part);

    int nred = use_part ? NRED : 0;
    fusedB_kernel<<<nred + NPAIR / HPB, 256, 0, stream>>>(
        hist, corr_index, ws_means, out_hist, out_avg,
        cpart, out_current, nred);
}